// Round 4
// baseline (69.610 us; speedup 1.0000x reference)
//
#include <hip/hip_runtime.h>
#include <stdint.h>

#define NB 16
#define NC 256
#define NH 48
#define NW 64
#define ND 21
#define HW (NH * NW)
#define ROW_ELEMS (NW * NC)   // one (b,y) row: 16384 bf16 = 32KB
#define NXCD 8
#define NWG (NB * NH)         // 768, divisible by 8

typedef __bf16 bf16x8 __attribute__((ext_vector_type(8)));
typedef float f32x4 __attribute__((ext_vector_type(4)));

// XCD-chunked bijective remap: XCD k (= blockIdx%8) gets contiguous wg range
// [k*96, k*96+96) = batches {2k, 2k+1}, all y. ws slice per XCD = 3MB < 4MB L2.
__device__ __forceinline__ int xcd_wg(int orig) {
    return (orig & (NXCD - 1)) * (NWG / NXCD) + (orig >> 3);
}

// ---- s1 (in1) LDS layout: [pos][c] bf16 with XOR swizzle, conflict-free b128.
__device__ __forceinline__ int sw_addr(int x, int chunk) {
    int cs = (chunk & ~7) | ((chunk ^ x) & 7);
    return x * 256 + (cs << 3);
}
// parity permutation: even x -> pos 0..31, odd x -> pos 32..63.
__device__ __forceinline__ int posx(int x) { return ((x & 1) << 5) | (x >> 1); }

// ---- ws (in2) GLOBAL layout: fragment order (see convert_in2). A wave's
// per-kb load is a fully coalesced contiguous 1KB; whole slice = 8KB.
__device__ __forceinline__ int frag_off(int w, int kb, int l) {
    return w * 4096 + kb * 512 + ((l ^ ((w & 3) << 1)) << 3);
}

__device__ __forceinline__ bf16x8 load_pack8(const float* __restrict__ p, int cbase) {
    bf16x8 v;
#pragma unroll
    for (int j = 0; j < 8; ++j)
        v[j] = (__bf16)p[(size_t)(cbase + j) * HW];
    return v;
}

// ---------- pre-pass: in2 fp32 [b][c][h][w] -> ws bf16 rows (fragment order) --
__global__ void __launch_bounds__(256, 4)
convert_in2(const float* __restrict__ in2, unsigned short* __restrict__ ws) {
    __shared__ unsigned short s[ROW_ELEMS];
    const int tid = threadIdx.x;
    const int wg = xcd_wg(blockIdx.x);
    const int b = wg / NH, y = wg % NH;
    const int x = tid & 63, g0 = tid >> 6;
    const int par = x & 1, m_lo = (x >> 1) & 15, nt = x >> 5;
    const int w = (nt << 1) | par;
    const float* p = in2 + ((size_t)b * NC * NH + y) * NW + x;
#pragma unroll
    for (int i = 0; i < 8; ++i) {
        const int chunk = g0 * 8 + i;
        const int kb = chunk >> 2, quad = chunk & 3;
        const int l = (quad << 4) | m_lo;
        bf16x8 v = load_pack8(p, chunk * 8);
        *(bf16x8*)&s[frag_off(w, kb, l)] = v;
    }
    __syncthreads();
    unsigned short* wr = ws + ((size_t)b * NH + y) * ROW_ELEMS;
#pragma unroll
    for (int i = 0; i < 8; ++i) {
        const int e = (i * 256 + tid) * 8;
        *(bf16x8*)(wr + e) = *(const bf16x8*)(s + e);
    }
}

// ---------- main: block per (b,y); TWO dy per barrier phase -----------------
__global__ void __launch_bounds__(256, 3)
corr_main(const float* __restrict__ in1, const unsigned short* __restrict__ ws,
          float* __restrict__ out) {
    __shared__ unsigned short s1[ROW_ELEMS];   // 32768 B, resident all kernel
    __shared__ float sout[4][ND * NW];         // 4 plane bufs, 21504 B (no pad:
                                               // drain is lane-consecutive;
                                               // scatter stride 66 = 2-way free)
    const int tid  = threadIdx.x;
    const int wg   = xcd_wg(blockIdx.x);
    const int b    = wg / NH, y = wg % NH;
    const int lane = tid & 63, wave = tid >> 6;
    const int m_lo = lane & 15, quad = lane >> 4;
    const int par  = wave & 1, nt = wave >> 1;

    // ---- stage in1 row into s1 (register-packed, conflict-free b128 writes)
    {
        const int x = tid & 63, g0 = tid >> 6;
        const int px = posx(x);
        const float* p = in1 + ((size_t)b * NC * NH + y) * NW + x;
#pragma unroll
        for (int i = 0; i < 8; ++i) {
            const int chunk = g0 * 8 + i;
            bf16x8 v = load_pack8(p, chunk * 8);
            *(bf16x8*)&s1[sw_addr(px, chunk)] = v;
        }
    }
    // zero all 4 plane bufs once (valid slots overwritten every phase; band-
    // invalid slots stay zero forever)
    for (int i = tid; i < 4 * ND * NW; i += 256) ((float*)sout)[i] = 0.0f;

    const int d0 = (y >= 20) ? 0 : (21 - y) >> 1;
    const int d1 = min(20, (67 - y) >> 1);       // n = d1-d0+1 >= 11 always
    const unsigned short* wsb = ws + (size_t)b * NH * ROW_ELEMS;
    const int slice_off = frag_off(wave, 0, lane);

    auto load_b = [&](bf16x8 (&bf)[8], int dyi) {
        const unsigned short* row = wsb + (size_t)(y - 20 + 2 * dyi) * ROW_ELEMS + slice_off;
#pragma unroll
        for (int kb = 0; kb < 8; ++kb)
            bf[kb] = *(const bf16x8*)&row[kb * 512];
    };

    // B register sets: B0/B2 alternate as bc0(p)/prefetch(p+2); B1 = bc1(p+1),
    // self-double-buffered (reloaded with p+3 after its last use each phase).
    bf16x8 B0[8], B1[8], B2[8];
    load_b(B0, d0);
    load_b(B1, d0 + 1);        // n>=11 so d0+1 <= d1 always
    __syncthreads();           // covers s1 staging for the per-phase A reads

    // ---- zero invalid dy planes (coalesced, nontemporal)
    float* outbase = out + (((size_t)b * (ND * ND)) * NH + (size_t)y) * NW;
    for (int dyi = 0; dyi < ND; ++dyi) {
        if (dyi >= d0 && dyi <= d1) continue;
        float* ob = outbase + (size_t)dyi * ND * HW;
        for (int i = tid; i < ND * NW; i += 256)
            __builtin_nontemporal_store(0.0f, &ob[(size_t)(i >> 6) * HW + (i & 63)]);
    }

    const float scale = 1.0f / 256.0f;
    const int xq    = 4 * quad;
    const int xph   = 16 * nt + m_lo;
    const int apos0 = par * 32 + m_lo;        // A row, mm=0
    const int apos1 = par * 32 + 16 + m_lo;   // A row, mm=1

    // one phase = two dy (p, p+1):
    //   1. drain-read planes p-2,p-1 from the other buf pair (hides under MFMAs)
    //   2. kb loop: 2 ds_read_b128 A-frags + 4 MFMA (both dy) — bc0/bc1 were
    //      prefetched LAST phase BEFORE last phase's stores, so the vmcnt wait
    //      here never waits on stores (ordered-queue vmcnt semantics)
    //   3. prefetch p+2 (into bn) and p+3 (into B1, after its last use)
    //   4. drain-store planes p-2,p-1 (fire-and-forget, never waited on)
    //   5. scatter p (and p+1) into this phase's buf pair
    //   6. lgkmcnt(0) + s_barrier — the ONLY hard wait, once per 2 dy
    auto phase = [&](bf16x8 (&bc0)[8], bf16x8 (&bc1)[8], bf16x8 (&bn)[8],
                     int p, bool have, int cb) {
        const bool two = (p + 1 <= d1);

        float dva[6], dvb[6];
        if (have) {
            const float* spa = sout[2 * (cb ^ 1)];
            const float* spb = sout[2 * (cb ^ 1) + 1];
#pragma unroll
            for (int k = 0; k < 5; ++k) {
                dva[k] = spa[(wave + 4 * k) * NW + lane];
                dvb[k] = spb[(wave + 4 * k) * NW + lane];
            }
            if (wave == 0) { dva[5] = spa[20 * NW + lane]; dvb[5] = spb[20 * NW + lane]; }
        }

        f32x4 a00 = {0,0,0,0}, a01 = {0,0,0,0}, a10 = {0,0,0,0}, a11 = {0,0,0,0};
#pragma unroll
        for (int kb = 0; kb < 8; ++kb) {
            bf16x8 af0 = *(const bf16x8*)&s1[sw_addr(apos0, 4 * kb + quad)];
            bf16x8 af1 = *(const bf16x8*)&s1[sw_addr(apos1, 4 * kb + quad)];
            a00 = __builtin_amdgcn_mfma_f32_16x16x32_bf16(af0, bc0[kb], a00, 0, 0, 0);
            a01 = __builtin_amdgcn_mfma_f32_16x16x32_bf16(af1, bc0[kb], a01, 0, 0, 0);
            a10 = __builtin_amdgcn_mfma_f32_16x16x32_bf16(af0, bc1[kb], a10, 0, 0, 0);
            a11 = __builtin_amdgcn_mfma_f32_16x16x32_bf16(af1, bc1[kb], a11, 0, 0, 0);
        }

        if (p + 2 <= d1) load_b(bn, p + 2);
        if (p + 3 <= d1) load_b(bc1, p + 3);   // B1's next value; bc1 consumed above

        if (have) {
            float* oba = outbase + (size_t)(p - 2) * ND * HW;
            float* obb = outbase + (size_t)(p - 1) * ND * HW;
#pragma unroll
            for (int k = 0; k < 5; ++k) {
                __builtin_nontemporal_store(dva[k] * scale, &oba[(size_t)(wave + 4 * k) * HW + lane]);
                __builtin_nontemporal_store(dvb[k] * scale, &obb[(size_t)(wave + 4 * k) * HW + lane]);
            }
            if (wave == 0) {
                __builtin_nontemporal_store(dva[5] * scale, &oba[(size_t)20 * HW + lane]);
                __builtin_nontemporal_store(dvb[5] * scale, &obb[(size_t)20 * HW + lane]);
            }
        }

        float* sb0 = sout[2 * cb];
        float* sb1 = sout[2 * cb + 1];
#pragma unroll
        for (int r = 0; r < 4; ++r) {
            {
                const int xh = xq + r;
                const int dxi = xph - xh + 10;
                if ((unsigned)dxi <= 20u) {
                    const int a = dxi * NW + 2 * xh + par;
                    sb0[a] = a00[r];
                    if (two) sb1[a] = a10[r];
                }
            }
            {
                const int xh = 16 + xq + r;
                const int dxi = xph - xh + 10;
                if ((unsigned)dxi <= 20u) {
                    const int a = dxi * NW + 2 * xh + par;
                    sb0[a] = a01[r];
                    if (two) sb1[a] = a11[r];
                }
            }
        }
        __asm__ __volatile__("s_waitcnt lgkmcnt(0)\n\ts_barrier" ::: "memory");
    };

    int p = d0;
    bool have = false;
    int lastcb, lastp;
    while (true) {
        phase(B0, B1, B2, p, have, 0);
        have = true; lastp = p; p += 2;
        if (p > d1) { lastcb = 0; break; }
        phase(B2, B1, B0, p, true, 1);
        lastp = p; p += 2;
        if (p > d1) { lastcb = 1; break; }
    }
    // epilogue: drain the final pair (visibility via last phase's barrier)
    {
        const bool two = (lastp + 1 <= d1);
        const float* spa = sout[2 * lastcb];
        const float* spb = sout[2 * lastcb + 1];
        float* oba = outbase + (size_t)lastp * ND * HW;
        float* obb = outbase + (size_t)(lastp + 1) * ND * HW;
        for (int i = tid; i < ND * NW; i += 256) {
            const int pl = i >> 6, x = i & 63;
            __builtin_nontemporal_store(spa[pl * NW + x] * scale, &oba[(size_t)pl * HW + x]);
            if (two)
                __builtin_nontemporal_store(spb[pl * NW + x] * scale, &obb[(size_t)pl * HW + x]);
        }
    }
}

// ---------- fallback (round-1 style) if ws is too small ----------------------
__global__ void __launch_bounds__(256, 2)
corr_fallback(const float* __restrict__ in1, const float* __restrict__ in2,
              float* __restrict__ out) {
    __shared__ unsigned short s1[ROW_ELEMS];
    __shared__ unsigned short s2[ROW_ELEMS];
    const int tid = threadIdx.x;
    const int b = blockIdx.x / NH, y = blockIdx.x % NH;
    const int lane = tid & 63, wave = tid >> 6;
    const int m_lo = lane & 15, quad = lane >> 4;
    const int asub = wave >> 1, bsub = wave & 1;
    {
        const int x = tid & 63, g0 = tid >> 6;
        const float* p = in1 + ((size_t)b * NC * NH + y) * NW + x;
        for (int i = 0; i < 8; ++i) {
            const int chunk = g0 * 8 + i;
            bf16x8 v = load_pack8(p, chunk * 8);
            *(bf16x8*)&s1[sw_addr(x, chunk)] = v;
        }
    }
    __syncthreads();
    bf16x8 afrag[2][8];
    for (int mm = 0; mm < 2; ++mm) {
        const int x = 32 * asub + 16 * mm + m_lo;
        for (int kb = 0; kb < 8; ++kb)
            afrag[mm][kb] = *(const bf16x8*)&s1[sw_addr(x, 4 * kb + quad)];
    }
    const float scale = 1.0f / 256.0f;
    for (int dyi = 0; dyi < ND; ++dyi) {
        const int ys = y + 2 * dyi - 20;
        float* ob = out + (((size_t)b * (ND * ND) + (size_t)dyi * ND) * NH + y) * NW;
        if ((unsigned)ys >= (unsigned)NH) {
            for (int i = tid; i < ND * NW; i += 256)
                ob[(size_t)(i >> 6) * HW + (i & 63)] = 0.0f;
            continue;
        }
        __syncthreads();
        {
            const int x = tid & 63, g0 = tid >> 6;
            const float* p = in2 + ((size_t)b * NC * NH + ys) * NW + x;
            for (int i = 0; i < 8; ++i) {
                const int chunk = g0 * 8 + i;
                bf16x8 v = load_pack8(p, chunk * 8);
                *(bf16x8*)&s2[sw_addr(x, chunk)] = v;
            }
        }
        __syncthreads();
        f32x4 acc[2][2];
        for (int mm = 0; mm < 2; ++mm)
            for (int nn = 0; nn < 2; ++nn) acc[mm][nn] = (f32x4){0.f, 0.f, 0.f, 0.f};
        for (int nn = 0; nn < 2; ++nn) {
            const int xpp = 32 * bsub + 16 * nn + m_lo;
            for (int kb = 0; kb < 8; ++kb) {
                bf16x8 bfrag = *(const bf16x8*)&s2[sw_addr(xpp, 4 * kb + quad)];
                acc[0][nn] = __builtin_amdgcn_mfma_f32_16x16x32_bf16(afrag[0][kb], bfrag, acc[0][nn], 0, 0, 0);
                acc[1][nn] = __builtin_amdgcn_mfma_f32_16x16x32_bf16(afrag[1][kb], bfrag, acc[1][nn], 0, 0, 0);
            }
        }
        for (int mm = 0; mm < 2; ++mm)
            for (int nn = 0; nn < 2; ++nn) {
                const int xb = 32 * asub + 16 * mm + 4 * quad;
                const int xpp = 32 * bsub + 16 * nn + m_lo;
                for (int r = 0; r < 4; ++r) {
                    const int x = xb + r, d = xpp - x;
                    if (d >= -20 && d <= 20 && !(d & 1))
                        ob[(size_t)((d + 20) >> 1) * HW + x] = acc[mm][nn][r] * scale;
                }
            }
        for (int i = tid; i < ND * 20; i += 256) {
            const int dxi = i / 20, j = i - dxi * 20;
            const int dx = 2 * dxi - 20, a = dx < 0 ? -dx : dx;
            if (j < a) {
                const int x = dx < 0 ? j : (NW - dx + j);
                ob[(size_t)dxi * HW + x] = 0.0f;
            }
        }
    }
}

extern "C" void kernel_launch(void* const* d_in, const int* in_sizes, int n_in,
                              void* d_out, int out_size, void* d_ws, size_t ws_size,
                              hipStream_t stream) {
    const float* in1 = (const float*)d_in[0];
    const float* in2 = (const float*)d_in[1];
    float* out = (float*)d_out;
    const size_t need = (size_t)NB * NH * ROW_ELEMS * sizeof(unsigned short);
    if (ws_size >= need) {
        convert_in2<<<dim3(NWG), dim3(256), 0, stream>>>(in2, (unsigned short*)d_ws);
        corr_main<<<dim3(NWG), dim3(256), 0, stream>>>(in1, (const unsigned short*)d_ws, out);
    } else {
        corr_fallback<<<dim3(NWG), dim3(256), 0, stream>>>(in1, in2, out);
    }
}

// Round 5
// 62.204 us; speedup vs baseline: 1.1190x; 1.1190x over previous
//
#include <hip/hip_runtime.h>
#include <stdint.h>

#define NB 16
#define NC 256
#define NH 48
#define NW 64
#define ND 21
#define HW (NH * NW)
#define ROW_ELEMS (NW * NC)   // one (b,y) row: 16384 bf16 = 32KB
#define SOUT_LD (NW + 1)      // padded: scatter bank = (dxi+x)%32, <=4-way
#define SOUT_SZ (ND * SOUT_LD)
#define NXCD 8
#define NWG (NB * NH)         // 768, divisible by 8

typedef __bf16 bf16x8 __attribute__((ext_vector_type(8)));
typedef float f32x4 __attribute__((ext_vector_type(4)));

// XCD-chunked bijective remap: XCD k (= blockIdx%8) gets contiguous wg range
// [k*96, k*96+96) = batches {2k, 2k+1}, all y. ws slice per XCD = 3MB < 4MB L2.
__device__ __forceinline__ int xcd_wg(int orig) {
    return (orig & (NXCD - 1)) * (NWG / NXCD) + (orig >> 3);
}

// ---- s1 (in1) LDS layout: [pos][c] bf16 with XOR swizzle, conflict-free b128.
__device__ __forceinline__ int sw_addr(int x, int chunk) {
    int cs = (chunk & ~7) | ((chunk ^ x) & 7);
    return x * 256 + (cs << 3);
}
// parity permutation: even x -> pos 0..31, odd x -> pos 32..63.
__device__ __forceinline__ int posx(int x) { return ((x & 1) << 5) | (x >> 1); }

// ---- ws (in2) GLOBAL layout: fragment order (see convert_in2). A wave's
// per-kb load is a fully coalesced contiguous 1KB; whole slice = 8KB.
__device__ __forceinline__ int frag_off(int w, int kb, int l) {
    return w * 4096 + kb * 512 + ((l ^ ((w & 3) << 1)) << 3);
}

__device__ __forceinline__ bf16x8 load_pack8(const float* __restrict__ p, int cbase) {
    bf16x8 v;
#pragma unroll
    for (int j = 0; j < 8; ++j)
        v[j] = (__bf16)p[(size_t)(cbase + j) * HW];
    return v;
}

// ---------- pre-pass: in2 fp32 [b][c][h][w] -> ws bf16 rows (fragment order) --
__global__ void __launch_bounds__(256, 4)
convert_in2(const float* __restrict__ in2, unsigned short* __restrict__ ws) {
    __shared__ unsigned short s[ROW_ELEMS];
    const int tid = threadIdx.x;
    const int wg = xcd_wg(blockIdx.x);
    const int b = wg / NH, y = wg % NH;
    const int x = tid & 63, g0 = tid >> 6;
    const int par = x & 1, m_lo = (x >> 1) & 15, nt = x >> 5;
    const int w = (nt << 1) | par;
    const float* p = in2 + ((size_t)b * NC * NH + y) * NW + x;
#pragma unroll
    for (int i = 0; i < 8; ++i) {
        const int chunk = g0 * 8 + i;
        const int kb = chunk >> 2, quad = chunk & 3;
        const int l = (quad << 4) | m_lo;
        bf16x8 v = load_pack8(p, chunk * 8);
        *(bf16x8*)&s[frag_off(w, kb, l)] = v;
    }
    __syncthreads();
    unsigned short* wr = ws + ((size_t)b * NH + y) * ROW_ELEMS;
#pragma unroll
    for (int i = 0; i < 8; ++i) {
        const int e = (i * 256 + tid) * 8;
        *(bf16x8*)(wr + e) = *(const bf16x8*)(s + e);
    }
}

// ---------- main: block per (b,y); TWO dy per phase; sout overlays s1 -------
__global__ void __launch_bounds__(256, 3)
corr_main(const float* __restrict__ in1, const unsigned short* __restrict__ ws,
          float* __restrict__ out) {
    // s1 (32KB, prologue-only: afrag lives in regs) overlaid by the 4 padded
    // epilogue plane buffers (21840 B). LDS_Block_Size = 32768 -> 3 blocks/CU.
    __shared__ __align__(16) unsigned char smem[32768];
    unsigned short* s1 = (unsigned short*)smem;
    float* soutf = (float*)smem;                 // [buf][ND][SOUT_LD]

    const int tid  = threadIdx.x;
    const int wg   = xcd_wg(blockIdx.x);
    const int b    = wg / NH, y = wg % NH;
    const int lane = tid & 63, wave = tid >> 6;
    const int m_lo = lane & 15, quad = lane >> 4;
    const int par  = wave & 1, nt = wave >> 1;

    const int d0 = (y >= 20) ? 0 : (21 - y) >> 1;
    const int d1 = min(20, (67 - y) >> 1);       // n = d1-d0+1 >= 11 always
    const unsigned short* wsb = ws + (size_t)b * NH * ROW_ELEMS;
    const int slice_off = frag_off(wave, 0, lane);

    auto load_b = [&](bf16x8 (&bf)[8], int dyi) {
        const unsigned short* row = wsb + (size_t)(y - 20 + 2 * dyi) * ROW_ELEMS + slice_off;
#pragma unroll
        for (int kb = 0; kb < 8; ++kb)
            bf[kb] = *(const bf16x8*)&row[kb * 512];
    };

    // ---- stage in1 row into s1 (register-packed, conflict-free b128 writes)
    {
        const int x = tid & 63, g0 = tid >> 6;
        const int px = posx(x);
        const float* p = in1 + ((size_t)b * NC * NH + y) * NW + x;
#pragma unroll
        for (int i = 0; i < 8; ++i) {
            const int chunk = g0 * 8 + i;
            bf16x8 v = load_pack8(p, chunk * 8);
            *(bf16x8*)&s1[sw_addr(px, chunk)] = v;
        }
    }
    // issue first two B prefetches; they stay in flight across the raw barriers
    bf16x8 B0[8], B1[8];
    load_b(B0, d0);
    load_b(B1, d0 + 1);        // n>=11 so d0+1 <= d1 always

    // barrier 1: s1 staging (ds_writes) visible
    __asm__ __volatile__("s_waitcnt lgkmcnt(0)\n\ts_barrier" ::: "memory");

    // ---- cache A in regs: A[pos = par*32+16*mm+m_lo][k]
    bf16x8 afrag[2][8];
#pragma unroll
    for (int mm = 0; mm < 2; ++mm) {
        const int pos = par * 32 + 16 * mm + m_lo;
#pragma unroll
        for (int kb = 0; kb < 8; ++kb)
            afrag[mm][kb] = *(const bf16x8*)&s1[sw_addr(pos, 4 * kb + quad)];
    }
    // barrier 2: all afrag ds_reads drained before the sout overlay is written
    __asm__ __volatile__("s_waitcnt lgkmcnt(0)\n\ts_barrier" ::: "memory");

    // zero all 4 plane bufs once (valid slots overwritten every phase; band-
    // invalid slots stay zero forever)
    for (int i = tid; i < 4 * SOUT_SZ; i += 256) soutf[i] = 0.0f;

    // ---- zero invalid dy planes (coalesced, nontemporal, fire-and-forget)
    float* outbase = out + (((size_t)b * (ND * ND)) * NH + (size_t)y) * NW;
    for (int dyi = 0; dyi < ND; ++dyi) {
        if (dyi >= d0 && dyi <= d1) continue;
        float* ob = outbase + (size_t)dyi * ND * HW;
        for (int i = tid; i < ND * NW; i += 256)
            __builtin_nontemporal_store(0.0f, &ob[(size_t)(i >> 6) * HW + (i & 63)]);
    }
    // barrier 3: sout zeroed before first scatter
    __asm__ __volatile__("s_waitcnt lgkmcnt(0)\n\ts_barrier" ::: "memory");

    const float scale = 1.0f / 256.0f;
    const int xq  = 4 * quad;
    const int xph = 16 * nt + m_lo;

    // one phase = two dy (p, p+1):
    //   1. drain-read planes p-2,p-1 from the other buf pair (hides under MFMAs)
    //   2. kb loop: 4 MFMAs (dy=p with B0, dy=p+1 with B1)
    //   3. reload B0 <- p+2, B1 <- p+3 (consumed next phase; one-phase distance;
    //      issued BEFORE this phase's global stores so their vmcnt wait next
    //      phase never drains stores — ordered-queue vmcnt semantics)
    //   4. drain-store planes p-2,p-1 (nontemporal, never waited on)
    //   5. scatter p (and p+1) into this phase's buf pair (padded: <=4-way)
    //   6. lgkmcnt(0) + s_barrier — the ONLY hard wait, once per 2 dy
    auto phase = [&](int p, bool have, int cb) {
        const bool two = (p + 1 <= d1);

        float dva[6], dvb[6];
        if (have) {
            const float* spa = soutf + (2 * (cb ^ 1)) * SOUT_SZ;
            const float* spb = soutf + (2 * (cb ^ 1) + 1) * SOUT_SZ;
#pragma unroll
            for (int k = 0; k < 5; ++k) {
                dva[k] = spa[(wave + 4 * k) * SOUT_LD + lane];
                dvb[k] = spb[(wave + 4 * k) * SOUT_LD + lane];
            }
            if (wave == 0) { dva[5] = spa[20 * SOUT_LD + lane]; dvb[5] = spb[20 * SOUT_LD + lane]; }
        }

        f32x4 a00 = {0,0,0,0}, a01 = {0,0,0,0}, a10 = {0,0,0,0}, a11 = {0,0,0,0};
#pragma unroll
        for (int kb = 0; kb < 8; ++kb) {
            a00 = __builtin_amdgcn_mfma_f32_16x16x32_bf16(afrag[0][kb], B0[kb], a00, 0, 0, 0);
            a01 = __builtin_amdgcn_mfma_f32_16x16x32_bf16(afrag[1][kb], B0[kb], a01, 0, 0, 0);
            a10 = __builtin_amdgcn_mfma_f32_16x16x32_bf16(afrag[0][kb], B1[kb], a10, 0, 0, 0);
            a11 = __builtin_amdgcn_mfma_f32_16x16x32_bf16(afrag[1][kb], B1[kb], a11, 0, 0, 0);
        }

        if (p + 2 <= d1) load_b(B0, p + 2);   // all MFMAs have issued: WAR safe
        if (p + 3 <= d1) load_b(B1, p + 3);   // (stale B1 on odd tail: unused)

        if (have) {
            float* oba = outbase + (size_t)(p - 2) * ND * HW;
            float* obb = outbase + (size_t)(p - 1) * ND * HW;
#pragma unroll
            for (int k = 0; k < 5; ++k) {
                __builtin_nontemporal_store(dva[k] * scale, &oba[(size_t)(wave + 4 * k) * HW + lane]);
                __builtin_nontemporal_store(dvb[k] * scale, &obb[(size_t)(wave + 4 * k) * HW + lane]);
            }
            if (wave == 0) {
                __builtin_nontemporal_store(dva[5] * scale, &oba[(size_t)20 * HW + lane]);
                __builtin_nontemporal_store(dvb[5] * scale, &obb[(size_t)20 * HW + lane]);
            }
        }

        float* sb0 = soutf + (2 * cb) * SOUT_SZ;
        float* sb1 = soutf + (2 * cb + 1) * SOUT_SZ;
#pragma unroll
        for (int r = 0; r < 4; ++r) {
            {
                const int xh = xq + r;                     // mm = 0
                const int dxi = xph - xh + 10;
                if ((unsigned)dxi <= 20u) {
                    const int a = dxi * SOUT_LD + 2 * xh + par;
                    sb0[a] = a00[r];
                    if (two) sb1[a] = a10[r];
                }
            }
            {
                const int xh = 16 + xq + r;                // mm = 1
                const int dxi = xph - xh + 10;
                if ((unsigned)dxi <= 20u) {
                    const int a = dxi * SOUT_LD + 2 * xh + par;
                    sb0[a] = a01[r];
                    if (two) sb1[a] = a11[r];
                }
            }
        }
        __asm__ __volatile__("s_waitcnt lgkmcnt(0)\n\ts_barrier" ::: "memory");
    };

    int p = d0, cb = 0, lastp, lastcb;
    bool have = false;
    for (;;) {
        phase(p, have, cb);
        lastp = p; lastcb = cb;
        have = true; p += 2; cb ^= 1;
        if (p > d1) break;
    }
    // epilogue: drain the final pair (visibility via last phase's barrier)
    {
        const bool two = (lastp + 1 <= d1);
        const float* spa = soutf + (2 * lastcb) * SOUT_SZ;
        const float* spb = soutf + (2 * lastcb + 1) * SOUT_SZ;
        float* oba = outbase + (size_t)lastp * ND * HW;
        float* obb = outbase + (size_t)(lastp + 1) * ND * HW;
        for (int i = tid; i < ND * NW; i += 256) {
            const int pl = i >> 6, x = i & 63;
            __builtin_nontemporal_store(spa[pl * SOUT_LD + x] * scale, &oba[(size_t)pl * HW + x]);
            if (two)
                __builtin_nontemporal_store(spb[pl * SOUT_LD + x] * scale, &obb[(size_t)pl * HW + x]);
        }
    }
}

// ---------- fallback (round-1 style) if ws is too small ----------------------
__global__ void __launch_bounds__(256, 2)
corr_fallback(const float* __restrict__ in1, const float* __restrict__ in2,
              float* __restrict__ out) {
    __shared__ unsigned short s1[ROW_ELEMS];
    __shared__ unsigned short s2[ROW_ELEMS];
    const int tid = threadIdx.x;
    const int b = blockIdx.x / NH, y = blockIdx.x % NH;
    const int lane = tid & 63, wave = tid >> 6;
    const int m_lo = lane & 15, quad = lane >> 4;
    const int asub = wave >> 1, bsub = wave & 1;
    {
        const int x = tid & 63, g0 = tid >> 6;
        const float* p = in1 + ((size_t)b * NC * NH + y) * NW + x;
        for (int i = 0; i < 8; ++i) {
            const int chunk = g0 * 8 + i;
            bf16x8 v = load_pack8(p, chunk * 8);
            *(bf16x8*)&s1[sw_addr(x, chunk)] = v;
        }
    }
    __syncthreads();
    bf16x8 afrag[2][8];
    for (int mm = 0; mm < 2; ++mm) {
        const int x = 32 * asub + 16 * mm + m_lo;
        for (int kb = 0; kb < 8; ++kb)
            afrag[mm][kb] = *(const bf16x8*)&s1[sw_addr(x, 4 * kb + quad)];
    }
    const float scale = 1.0f / 256.0f;
    for (int dyi = 0; dyi < ND; ++dyi) {
        const int ys = y + 2 * dyi - 20;
        float* ob = out + (((size_t)b * (ND * ND) + (size_t)dyi * ND) * NH + y) * NW;
        if ((unsigned)ys >= (unsigned)NH) {
            for (int i = tid; i < ND * NW; i += 256)
                ob[(size_t)(i >> 6) * HW + (i & 63)] = 0.0f;
            continue;
        }
        __syncthreads();
        {
            const int x = tid & 63, g0 = tid >> 6;
            const float* p = in2 + ((size_t)b * NC * NH + ys) * NW + x;
            for (int i = 0; i < 8; ++i) {
                const int chunk = g0 * 8 + i;
                bf16x8 v = load_pack8(p, chunk * 8);
                *(bf16x8*)&s2[sw_addr(x, chunk)] = v;
            }
        }
        __syncthreads();
        f32x4 acc[2][2];
        for (int mm = 0; mm < 2; ++mm)
            for (int nn = 0; nn < 2; ++nn) acc[mm][nn] = (f32x4){0.f, 0.f, 0.f, 0.f};
        for (int nn = 0; nn < 2; ++nn) {
            const int xpp = 32 * bsub + 16 * nn + m_lo;
            for (int kb = 0; kb < 8; ++kb) {
                bf16x8 bfrag = *(const bf16x8*)&s2[sw_addr(xpp, 4 * kb + quad)];
                acc[0][nn] = __builtin_amdgcn_mfma_f32_16x16x32_bf16(afrag[0][kb], bfrag, acc[0][nn], 0, 0, 0);
                acc[1][nn] = __builtin_amdgcn_mfma_f32_16x16x32_bf16(afrag[1][kb], bfrag, acc[1][nn], 0, 0, 0);
            }
        }
        for (int mm = 0; mm < 2; ++mm)
            for (int nn = 0; nn < 2; ++nn) {
                const int xb = 32 * asub + 16 * mm + 4 * quad;
                const int xpp = 32 * bsub + 16 * nn + m_lo;
                for (int r = 0; r < 4; ++r) {
                    const int x = xb + r, d = xpp - x;
                    if (d >= -20 && d <= 20 && !(d & 1))
                        ob[(size_t)((d + 20) >> 1) * HW + x] = acc[mm][nn][r] * scale;
                }
            }
        for (int i = tid; i < ND * 20; i += 256) {
            const int dxi = i / 20, j = i - dxi * 20;
            const int dx = 2 * dxi - 20, a = dx < 0 ? -dx : dx;
            if (j < a) {
                const int x = dx < 0 ? j : (NW - dx + j);
                ob[(size_t)dxi * HW + x] = 0.0f;
            }
        }
    }
}

extern "C" void kernel_launch(void* const* d_in, const int* in_sizes, int n_in,
                              void* d_out, int out_size, void* d_ws, size_t ws_size,
                              hipStream_t stream) {
    const float* in1 = (const float*)d_in[0];
    const float* in2 = (const float*)d_in[1];
    float* out = (float*)d_out;
    const size_t need = (size_t)NB * NH * ROW_ELEMS * sizeof(unsigned short);
    if (ws_size >= need) {
        convert_in2<<<dim3(NWG), dim3(256), 0, stream>>>(in2, (unsigned short*)d_ws);
        corr_main<<<dim3(NWG), dim3(256), 0, stream>>>(in1, (const unsigned short*)d_ws, out);
    } else {
        corr_fallback<<<dim3(NWG), dim3(256), 0, stream>>>(in1, in2, out);
    }
}

// Round 6
// 58.959 us; speedup vs baseline: 1.1806x; 1.0550x over previous
//
#include <hip/hip_runtime.h>
#include <stdint.h>

#define NB 16
#define NC 256
#define NH 48
#define NW 64
#define ND 21
#define HW (NH * NW)
#define ROW_ELEMS (NW * NC)   // one (b,y) row: 16384 bf16 = 32KB
#define NXCD 8
#define NWG (NB * NH)         // 768
#define SO_LD 33              // sout leading dim: 32 local cols + 1 pad
#define SO_SZ (ND * SO_LD)

typedef __bf16 bf16x8 __attribute__((ext_vector_type(8)));
typedef float f32x4 __attribute__((ext_vector_type(4)));

// convert grid (768): XCD k owns wg [k*96, k*96+96) = batches {2k,2k+1}
__device__ __forceinline__ int xcd_wg(int orig) {
    return (orig & (NXCD - 1)) * (NWG / NXCD) + (orig >> 3);
}

// half-row s1 LDS layout: 32 lpos x 256 c bf16 (16KB), XOR-swizzled chunks
__device__ __forceinline__ int swh(int lpos, int chunk) {
    int cs = (chunk & ~7) | ((chunk ^ lpos) & 7);
    return lpos * 256 + (cs << 3);
}

// full-row s1 swizzle (fallback kernel only)
__device__ __forceinline__ int sw_addr(int x, int chunk) {
    int cs = (chunk & ~7) | ((chunk ^ x) & 7);
    return x * 256 + (cs << 3);
}

// ws (in2) GLOBAL fragment order (unchanged): wave slice = contiguous 8KB,
// per-kb load = contiguous 1KB.
__device__ __forceinline__ int frag_off(int w, int kb, int l) {
    return w * 4096 + kb * 512 + ((l ^ ((w & 3) << 1)) << 3);
}

__device__ __forceinline__ bf16x8 load_pack8(const float* __restrict__ p, int cbase) {
    bf16x8 v;
#pragma unroll
    for (int j = 0; j < 8; ++j)
        v[j] = (__bf16)p[(size_t)(cbase + j) * HW];
    return v;
}

// ---------- pre-pass: in2 fp32 [b][c][h][w] -> ws bf16 rows (fragment order) --
__global__ void __launch_bounds__(256, 4)
convert_in2(const float* __restrict__ in2, unsigned short* __restrict__ ws) {
    __shared__ unsigned short s[ROW_ELEMS];
    const int tid = threadIdx.x;
    const int wg = xcd_wg(blockIdx.x);
    const int b = wg / NH, y = wg % NH;
    const int x = tid & 63, g0 = tid >> 6;
    const int par = x & 1, m_lo = (x >> 1) & 15, nt = x >> 5;
    const int w = (nt << 1) | par;
    const float* p = in2 + ((size_t)b * NC * NH + y) * NW + x;
#pragma unroll
    for (int i = 0; i < 8; ++i) {
        const int chunk = g0 * 8 + i;
        const int kb = chunk >> 2, quad = chunk & 3;
        const int l = (quad << 4) | m_lo;
        bf16x8 v = load_pack8(p, chunk * 8);
        *(bf16x8*)&s[frag_off(w, kb, l)] = v;
    }
    __syncthreads();
    unsigned short* wr = ws + ((size_t)b * NH + y) * ROW_ELEMS;
#pragma unroll
    for (int i = 0; i < 8; ++i) {
        const int e = (i * 256 + tid) * 8;
        *(bf16x8*)(wr + e) = *(const bf16x8*)(s + e);
    }
}

// ---------- main: block = (b, y, mt-half, dy-half); 3072 blocks -------------
// Per-wave state halved (afrag[8], one acc) -> 4 waves/SIMD; LDS 16KB.
__global__ void __launch_bounds__(256, 4)
corr_main(const float* __restrict__ in1, const unsigned short* __restrict__ ws,
          float* __restrict__ out) {
    __shared__ __align__(16) unsigned char smem[16384];
    unsigned short* s1h = (unsigned short*)smem;   // prologue: half in1 row
    float* soutf = (float*)smem;                   // loop: 2 x [ND][SO_LD]

    const int tid  = threadIdx.x;
    // decode (XCD-chunked): all 4 sub-blocks of a (b,y) land on one XCD
    const int xcd  = blockIdx.x & 7;
    const int u    = blockIdx.x >> 3;              // [0, 384)
    const int wg   = xcd * (NWG / NXCD) + (u >> 2);
    const int mt   = u & 1, half = (u >> 1) & 1;
    const int b    = wg / NH, y = wg % NH;
    const int lane = tid & 63, wave = tid >> 6;
    const int m_lo = lane & 15, quad = lane >> 4;
    const int par  = wave & 1, nt = wave >> 1;

    const int d0 = (y >= 20) ? 0 : (21 - y) >> 1;
    const int d1 = min(20, (67 - y) >> 1);
    const int r0 = half * 11, r1 = half ? ND : 11;   // this block's dy range
    const int e0 = max(d0, r0), e1 = min(d1, r1 - 1);

    float* outbase = out + (((size_t)b * (ND * ND)) * NH + (size_t)y) * NW;
    const int xl = tid & 31, dpz = tid >> 5;         // drain/zero: col, plane base

    auto zero_plane = [&](int dyi) {
        float* ob = outbase + (size_t)dyi * ND * HW;
#pragma unroll
        for (int k = 0; k < 3; ++k) {
            const int dxi = dpz + 8 * k;
            if (dxi < ND)
                __builtin_nontemporal_store(0.0f, &ob[(size_t)dxi * HW + 32 * mt + xl]);
        }
    };
    if (e0 > e1) {   // no valid dy in range: zero our quarter and exit
        for (int dyi = r0; dyi < r1; ++dyi) zero_plane(dyi);
        return;
    }

    // ---- stage this mt-half of the in1 row (32 x-cols, 16KB)
    {
        const int x = 32 * mt + (tid & 31), g0 = tid >> 5;
        const int lpos = ((x & 1) << 4) | ((x >> 1) & 15);   // par*16 + m_lo
        const float* p = in1 + ((size_t)b * NC * NH + y) * NW + x;
#pragma unroll
        for (int i = 0; i < 4; ++i) {
            const int chunk = g0 * 4 + i;
            bf16x8 v = load_pack8(p, chunk * 8);
            *(bf16x8*)&s1h[swh(lpos, chunk)] = v;
        }
    }

    const unsigned short* wsb = ws + (size_t)b * NH * ROW_ELEMS;
    const int slice_off = frag_off(wave, 0, lane);
    auto load_b = [&](bf16x8 (&bf)[8], int dyi) {
        const unsigned short* row = wsb + (size_t)(y - 20 + 2 * dyi) * ROW_ELEMS + slice_off;
#pragma unroll
        for (int kb = 0; kb < 8; ++kb)
            bf[kb] = *(const bf16x8*)&row[kb * 512];
    };

    bf16x8 B0[8], B1[8];
    load_b(B0, e0);
    load_b(B1, min(e0 + 1, e1));   // dup-safe when n==1 (unused)

    // zero invalid dy planes in our range (nt stores, fire-and-forget)
    for (int dyi = r0; dyi < r1; ++dyi)
        if (dyi < e0 || dyi > e1) zero_plane(dyi);

    // barrier 1: s1h staging visible
    __asm__ __volatile__("s_waitcnt lgkmcnt(0)\n\ts_barrier" ::: "memory");

    // ---- A fragments for this wave: pos = par*32 + 16*mt + m_lo
    bf16x8 afrag[8];
    {
        const int lpa = par * 16 + m_lo;
#pragma unroll
        for (int kb = 0; kb < 8; ++kb)
            afrag[kb] = *(const bf16x8*)&s1h[swh(lpa, 4 * kb + quad)];
    }
    // barrier 2: afrag reads drained before sout overlays s1h
    __asm__ __volatile__("s_waitcnt lgkmcnt(0)\n\ts_barrier" ::: "memory");

    for (int i = tid; i < 2 * SO_SZ; i += 256) soutf[i] = 0.0f;
    // barrier 3: sout zeroed before first scatter
    __asm__ __volatile__("s_waitcnt lgkmcnt(0)\n\ts_barrier" ::: "memory");

    const float scale = 1.0f / 256.0f;
    const int xq  = 4 * quad;
    const int xph = 16 * nt + m_lo;   // x' half-index, global in [0,32)

    // one dy step: drain ds_reads (hide under MFMAs) -> 8 MFMAs -> prefetch
    // t+2 into the set just consumed -> drain nt-stores -> scatter -> lgkm+bar
    auto step = [&](bf16x8 (&bc)[8], int t, int cb, bool have) {
        float dv[3];
        const float* sp = soutf + (cb ^ 1) * SO_SZ;
        if (have) {
#pragma unroll
            for (int k = 0; k < 3; ++k) {
                const int dxi = dpz + 8 * k;
                if (dxi < ND) dv[k] = sp[dxi * SO_LD + xl];
            }
        }

        f32x4 acc = {0.f, 0.f, 0.f, 0.f};
#pragma unroll
        for (int kb = 0; kb < 8; ++kb)
            acc = __builtin_amdgcn_mfma_f32_16x16x32_bf16(afrag[kb], bc[kb], acc, 0, 0, 0);

        if (t + 2 <= e1) load_b(bc, t + 2);   // consumed 2 steps later

        if (have) {
            float* ob = outbase + (size_t)(t - 1) * ND * HW;
#pragma unroll
            for (int k = 0; k < 3; ++k) {
                const int dxi = dpz + 8 * k;
                if (dxi < ND)
                    __builtin_nontemporal_store(dv[k] * scale,
                                                &ob[(size_t)dxi * HW + 32 * mt + xl]);
            }
        }

        float* sb = soutf + cb * SO_SZ;
#pragma unroll
        for (int r = 0; r < 4; ++r) {
            const int lxh = xq + r;                       // local half-col [0,16)
            const int dxi = xph - (16 * mt + lxh) + 10;
            if ((unsigned)dxi <= 20u)
                sb[dxi * SO_LD + 2 * lxh + par] = acc[r];  // bank=(dxi+..)%32: spread
        }
        __asm__ __volatile__("s_waitcnt lgkmcnt(0)\n\ts_barrier" ::: "memory");
    };

    int t = e0, cb = 0, lastcb = 0;
    bool have = false;
    for (;;) {
        step(B0, t, cb, have); lastcb = cb;
        if (++t > e1) break;
        cb ^= 1; have = true;
        step(B1, t, cb, have); lastcb = cb;
        if (++t > e1) break;
        cb ^= 1;
    }
    // epilogue: drain plane e1 (visibility via last step's barrier)
    {
        const float* sp = soutf + lastcb * SO_SZ;
        float* ob = outbase + (size_t)e1 * ND * HW;
#pragma unroll
        for (int k = 0; k < 3; ++k) {
            const int dxi = dpz + 8 * k;
            if (dxi < ND)
                __builtin_nontemporal_store(sp[dxi * SO_LD + xl] * scale,
                                            &ob[(size_t)dxi * HW + 32 * mt + xl]);
        }
    }
}

// ---------- fallback (round-1 style) if ws is too small ----------------------
__global__ void __launch_bounds__(256, 2)
corr_fallback(const float* __restrict__ in1, const float* __restrict__ in2,
              float* __restrict__ out) {
    __shared__ unsigned short s1[ROW_ELEMS];
    __shared__ unsigned short s2[ROW_ELEMS];
    const int tid = threadIdx.x;
    const int b = blockIdx.x / NH, y = blockIdx.x % NH;
    const int lane = tid & 63, wave = tid >> 6;
    const int m_lo = lane & 15, quad = lane >> 4;
    const int asub = wave >> 1, bsub = wave & 1;
    {
        const int x = tid & 63, g0 = tid >> 6;
        const float* p = in1 + ((size_t)b * NC * NH + y) * NW + x;
        for (int i = 0; i < 8; ++i) {
            const int chunk = g0 * 8 + i;
            bf16x8 v = load_pack8(p, chunk * 8);
            *(bf16x8*)&s1[sw_addr(x, chunk)] = v;
        }
    }
    __syncthreads();
    bf16x8 afrag[2][8];
    for (int mm = 0; mm < 2; ++mm) {
        const int x = 32 * asub + 16 * mm + m_lo;
        for (int kb = 0; kb < 8; ++kb)
            afrag[mm][kb] = *(const bf16x8*)&s1[sw_addr(x, 4 * kb + quad)];
    }
    const float scale = 1.0f / 256.0f;
    for (int dyi = 0; dyi < ND; ++dyi) {
        const int ys = y + 2 * dyi - 20;
        float* ob = out + (((size_t)b * (ND * ND) + (size_t)dyi * ND) * NH + y) * NW;
        if ((unsigned)ys >= (unsigned)NH) {
            for (int i = tid; i < ND * NW; i += 256)
                ob[(size_t)(i >> 6) * HW + (i & 63)] = 0.0f;
            continue;
        }
        __syncthreads();
        {
            const int x = tid & 63, g0 = tid >> 6;
            const float* p = in2 + ((size_t)b * NC * NH + ys) * NW + x;
            for (int i = 0; i < 8; ++i) {
                const int chunk = g0 * 8 + i;
                bf16x8 v = load_pack8(p, chunk * 8);
                *(bf16x8*)&s2[sw_addr(x, chunk)] = v;
            }
        }
        __syncthreads();
        f32x4 acc[2][2];
        for (int mm = 0; mm < 2; ++mm)
            for (int nn = 0; nn < 2; ++nn) acc[mm][nn] = (f32x4){0.f, 0.f, 0.f, 0.f};
        for (int nn = 0; nn < 2; ++nn) {
            const int xpp = 32 * bsub + 16 * nn + m_lo;
            for (int kb = 0; kb < 8; ++kb) {
                bf16x8 bfrag = *(const bf16x8*)&s2[sw_addr(xpp, 4 * kb + quad)];
                acc[0][nn] = __builtin_amdgcn_mfma_f32_16x16x32_bf16(afrag[0][kb], bfrag, acc[0][nn], 0, 0, 0);
                acc[1][nn] = __builtin_amdgcn_mfma_f32_16x16x32_bf16(afrag[1][kb], bfrag, acc[1][nn], 0, 0, 0);
            }
        }
        for (int mm = 0; mm < 2; ++mm)
            for (int nn = 0; nn < 2; ++nn) {
                const int xb = 32 * asub + 16 * mm + 4 * quad;
                const int xpp = 32 * bsub + 16 * nn + m_lo;
                for (int r = 0; r < 4; ++r) {
                    const int x = xb + r, d = xpp - x;
                    if (d >= -20 && d <= 20 && !(d & 1))
                        ob[(size_t)((d + 20) >> 1) * HW + x] = acc[mm][nn][r] * scale;
                }
            }
        for (int i = tid; i < ND * 20; i += 256) {
            const int dxi = i / 20, j = i - dxi * 20;
            const int dx = 2 * dxi - 20, a = dx < 0 ? -dx : dx;
            if (j < a) {
                const int x = dx < 0 ? j : (NW - dx + j);
                ob[(size_t)dxi * HW + x] = 0.0f;
            }
        }
    }
}

extern "C" void kernel_launch(void* const* d_in, const int* in_sizes, int n_in,
                              void* d_out, int out_size, void* d_ws, size_t ws_size,
                              hipStream_t stream) {
    const float* in1 = (const float*)d_in[0];
    const float* in2 = (const float*)d_in[1];
    float* out = (float*)d_out;
    const size_t need = (size_t)NB * NH * ROW_ELEMS * sizeof(unsigned short);
    if (ws_size >= need) {
        convert_in2<<<dim3(NWG), dim3(256), 0, stream>>>(in2, (unsigned short*)d_ws);
        corr_main<<<dim3(NWG * 4), dim3(256), 0, stream>>>(in1, (const unsigned short*)d_ws, out);
    } else {
        corr_fallback<<<dim3(NWG), dim3(256), 0, stream>>>(in1, in2, out);
    }
}

// Round 7
// 49.380 us; speedup vs baseline: 1.4097x; 1.1940x over previous
//
#include <hip/hip_runtime.h>
#include <stdint.h>

#define NB 16
#define NC 256
#define NH 48
#define NW 64
#define ND 21
#define HW (NH * NW)
#define ROW_ELEMS (NW * NC)   // one (b,y) row: 16384 bf16 = 32KB
#define NXCD 8
#define NWG (NB * NH)         // 768 (convert grid)
#define SO_LD 65              // padded plane leading dim
#define SO_SZ (ND * SO_LD)    // 1365 floats per plane

typedef __bf16 bf16x8 __attribute__((ext_vector_type(8)));
typedef float f32x4 __attribute__((ext_vector_type(4)));

// convert grid (768): XCD k owns wg [k*96, k*96+96) = batches {2k,2k+1}
__device__ __forceinline__ int xcd_wg(int orig) {
    return (orig & (NXCD - 1)) * (NWG / NXCD) + (orig >> 3);
}

// full-row LDS layout [pos][c] bf16, XOR-swizzled 16B chunks (conflict-free b128)
__device__ __forceinline__ int sw_addr(int x, int chunk) {
    int cs = (chunk & ~7) | ((chunk ^ x) & 7);
    return x * 256 + (cs << 3);
}
// parity permutation: even x -> pos 0..31, odd x -> pos 32..63
__device__ __forceinline__ int posx(int x) { return ((x & 1) << 5) | (x >> 1); }

// ws (in2) GLOBAL fragment order: slice w=(nt<<1)|par, per-kb 1KB contiguous
__device__ __forceinline__ int frag_off(int w, int kb, int l) {
    return w * 4096 + kb * 512 + ((l ^ ((w & 3) << 1)) << 3);
}

__device__ __forceinline__ bf16x8 load_pack8(const float* __restrict__ p, int cbase) {
    bf16x8 v;
#pragma unroll
    for (int j = 0; j < 8; ++j)
        v[j] = (__bf16)p[(size_t)(cbase + j) * HW];
    return v;
}

// ---------- pre-pass: in2 fp32 [b][c][h][w] -> ws bf16 rows (fragment order) --
__global__ void __launch_bounds__(256, 4)
convert_in2(const float* __restrict__ in2, unsigned short* __restrict__ ws) {
    __shared__ unsigned short s[ROW_ELEMS];
    const int tid = threadIdx.x;
    const int wg = xcd_wg(blockIdx.x);
    const int b = wg / NH, y = wg % NH;
    const int x = tid & 63, g0 = tid >> 6;
    const int par = x & 1, m_lo = (x >> 1) & 15, nt = x >> 5;
    const int w = (nt << 1) | par;
    const float* p = in2 + ((size_t)b * NC * NH + y) * NW + x;
#pragma unroll
    for (int i = 0; i < 8; ++i) {
        const int chunk = g0 * 8 + i;
        const int kb = chunk >> 2, quad = chunk & 3;
        const int l = (quad << 4) | m_lo;
        bf16x8 v = load_pack8(p, chunk * 8);
        *(bf16x8*)&s[frag_off(w, kb, l)] = v;
    }
    __syncthreads();
    unsigned short* wr = ws + ((size_t)b * NH + y) * ROW_ELEMS;
#pragma unroll
    for (int i = 0; i < 8; ++i) {
        const int e = (i * 256 + tid) * 8;
        *(bf16x8*)(wr + e) = *(const bf16x8*)(s + e);
    }
}

// ---------- main: block = (b, parity, 6-y group, ys-half); 256 blocks -------
// Each ws row staged ONCE per block and consumed by 6 y's (12 waves): the
// per-CU B-byte volume (the measured binding resource R2-R6) drops 3.8x.
__global__ void __launch_bounds__(768, 3)
corr_main(const float* __restrict__ in1, const unsigned short* __restrict__ ws,
          float* __restrict__ out) {
    // [0,32768): B row buffer (ws fragment layout, single-buffered)
    // [32768, 65528): 6 sout plane buffers [ND][SO_LD]
    // prologue overlays [0,65536) as two A-row staging regions
    __shared__ __align__(16) unsigned char smem[65536];
    unsigned short* bbuf  = (unsigned short*)smem;
    float*          soutf = (float*)(smem + 32768);
    unsigned short* areg0 = (unsigned short*)smem;
    unsigned short* areg1 = (unsigned short*)(smem + 32768);

    const int tid  = threadIdx.x;
    const int bid  = blockIdx.x;
    const int xcd  = bid & 7;                  // all blocks of b on one XCD
    const int u    = bid >> 3;                 // 0..31
    const int b    = 2 * xcd + (u >> 4);
    const int v    = u & 15;
    const int P    = v & 1, g = (v >> 1) & 3, half = v >> 3;
    const int y0   = 12 * g + P;
    const int lane = tid & 63, wave = tid >> 6;   // 12 waves
    const int m_lo = lane & 15, quad = lane >> 4;
    const int par  = wave & 1, yy = wave >> 1;    // wave = (par, yy)
    const int y    = y0 + 2 * yy;                 // this wave's output row

    // ys span (parity P) covering all 6 y's; split in half across 2 blocks
    const int lo = max(y0 - 20, P);
    const int hi = min(y0 + 30, 46 + P);
    const int n  = ((hi - lo) >> 1) + 1;          // 16..22
    const int n0 = (n + 1) >> 1;
    const int lo_h = half ? (lo + 2 * n0) : lo;
    const int nh   = half ? (n - n0) : n0;

    const unsigned short* wsb = ws + (size_t)b * NH * ROW_ELEMS;

    // issue first B row load early (lands under the A-staging prologue)
    bf16x8 Bst[3];
    {
        const unsigned short* row = wsb + (size_t)lo_h * ROW_ELEMS;
        Bst[0] = *(const bf16x8*)&row[tid * 8];
        Bst[1] = *(const bf16x8*)&row[(768 + tid) * 8];
        if (tid < 512) Bst[2] = *(const bf16x8*)&row[(1536 + tid) * 8];
    }

    // ---- prologue: stage 6 in1 rows (2 per round) and extract A fragments
    bf16x8 afrag[2][8];
#pragma unroll 1
    for (int rnd = 0; rnd < 3; ++rnd) {
        const int yA = y0 + 4 * rnd;              // rows yA, yA+2
#pragma unroll
        for (int i = 0; i < 6; ++i) {
            const int uu = i * 768 + tid;
            if (uu < 4096) {
                const int row = uu >> 11, cu = uu & 2047;
                const int x = cu & 63, chunk = cu >> 6;
                const float* p = in1 + ((size_t)b * NC * NH + (yA + 2 * row)) * NW + x;
                bf16x8 vv = load_pack8(p, chunk * 8);
                unsigned short* dst = row ? areg1 : areg0;
                *(bf16x8*)&dst[sw_addr(posx(x), chunk)] = vv;
            }
        }
        __asm__ __volatile__("s_waitcnt lgkmcnt(0)\n\ts_barrier" ::: "memory");
        if ((yy >> 1) == rnd) {
            const unsigned short* src = (yy & 1) ? areg1 : areg0;
            const int pos0 = par * 32 + m_lo;
#pragma unroll
            for (int kb = 0; kb < 8; ++kb) {
                afrag[0][kb] = *(const bf16x8*)&src[sw_addr(pos0,      4 * kb + quad)];
                afrag[1][kb] = *(const bf16x8*)&src[sw_addr(pos0 + 16, 4 * kb + quad)];
            }
        }
        __asm__ __volatile__("s_waitcnt lgkmcnt(0)\n\ts_barrier" ::: "memory");
    }

    // first B row into bbuf; zero sout (pad slots stay zero forever)
    *(bf16x8*)&bbuf[tid * 8] = Bst[0];
    *(bf16x8*)&bbuf[(768 + tid) * 8] = Bst[1];
    if (tid < 512) *(bf16x8*)&bbuf[(1536 + tid) * 8] = Bst[2];
    for (int i = tid; i < 6 * SO_SZ; i += 768) soutf[i] = 0.0f;

    // zero this half's invalid dy planes (per wave-pair, nontemporal)
    float* outyy = out + (size_t)b * (ND * ND) * HW + (size_t)y * NW;
    const int d0 = (y >= 20) ? 0 : ((21 - y) >> 1);
    const int d1 = min(20, (67 - y) >> 1);
    const int zlo = half ? (d1 + 1) : 0;
    const int zhi = half ? ND : d0;
    const int t2  = par * 64 + lane;              // 0..127 in wave-pair
    for (int z = zlo; z < zhi; ++z) {
        float* ob = outyy + (size_t)z * ND * HW;
#pragma unroll
        for (int i = 0; i < 11; ++i) {
            const int e = i * 128 + t2;
            if (e < ND * NW)
                __builtin_nontemporal_store(0.0f, &ob[(size_t)(e >> 6) * HW + (e & 63)]);
        }
    }
    __asm__ __volatile__("s_waitcnt lgkmcnt(0)\n\ts_barrier" ::: "memory");

    const float scale = 1.0f / 256.0f;
    const int boff0 = frag_off((0 << 1) | par, 0, lane);   // N-tile 0 slice
    const int boff1 = frag_off((1 << 1) | par, 0, lane);   // N-tile 1 slice

    // step: [prefetch next row -> regs | compute+scatter from bbuf] bar
    //       [write next row -> bbuf | drain plane -> global nt] bar
    for (int k = 0; k < nh; ++k) {
        const int ys = lo_h + 2 * k;
        if (k + 1 < nh) {
            const unsigned short* row = wsb + (size_t)(ys + 2) * ROW_ELEMS;
            Bst[0] = *(const bf16x8*)&row[tid * 8];
            Bst[1] = *(const bf16x8*)&row[(768 + tid) * 8];
            if (tid < 512) Bst[2] = *(const bf16x8*)&row[(1536 + tid) * 8];
        }
        const int dyi = ((ys - y) >> 1) + 10;
        const bool valid = (unsigned)dyi <= 20u;   // wave-uniform

        if (valid) {
            f32x4 a00 = {0,0,0,0}, a01 = {0,0,0,0}, a10 = {0,0,0,0}, a11 = {0,0,0,0};
#pragma unroll
            for (int kb = 0; kb < 8; ++kb) {
                bf16x8 b0 = *(const bf16x8*)&bbuf[boff0 + kb * 512];
                bf16x8 b1 = *(const bf16x8*)&bbuf[boff1 + kb * 512];
                a00 = __builtin_amdgcn_mfma_f32_16x16x32_bf16(afrag[0][kb], b0, a00, 0, 0, 0);
                a10 = __builtin_amdgcn_mfma_f32_16x16x32_bf16(afrag[1][kb], b0, a10, 0, 0, 0);
                a01 = __builtin_amdgcn_mfma_f32_16x16x32_bf16(afrag[0][kb], b1, a01, 0, 0, 0);
                a11 = __builtin_amdgcn_mfma_f32_16x16x32_bf16(afrag[1][kb], b1, a11, 0, 0, 0);
            }
            float* sp = soutf + yy * SO_SZ;
#pragma unroll
            for (int mm = 0; mm < 2; ++mm)
#pragma unroll
            for (int nn = 0; nn < 2; ++nn)
#pragma unroll
            for (int r = 0; r < 4; ++r) {
                const int xh  = 16 * mm + 4 * quad + r;
                const int dxi = (16 * nn + m_lo) - xh + 10;
                const float vv = mm == 0 ? (nn == 0 ? a00[r] : a01[r])
                                         : (nn == 0 ? a10[r] : a11[r]);
                if ((unsigned)dxi <= 20u)
                    sp[dxi * SO_LD + 2 * xh + par] = vv;
            }
        }
        __asm__ __volatile__("s_waitcnt lgkmcnt(0)\n\ts_barrier" ::: "memory");

        if (k + 1 < nh) {
            *(bf16x8*)&bbuf[tid * 8] = Bst[0];
            *(bf16x8*)&bbuf[(768 + tid) * 8] = Bst[1];
            if (tid < 512) *(bf16x8*)&bbuf[(1536 + tid) * 8] = Bst[2];
        }
        if (valid) {
            const float* sp = soutf + yy * SO_SZ;
            float* ob = outyy + (size_t)dyi * ND * HW;
#pragma unroll
            for (int i = 0; i < 11; ++i) {
                const int e = i * 128 + t2;
                if (e < ND * NW)
                    __builtin_nontemporal_store(sp[(e >> 6) * SO_LD + (e & 63)] * scale,
                                                &ob[(size_t)(e >> 6) * HW + (e & 63)]);
            }
        }
        __asm__ __volatile__("s_waitcnt lgkmcnt(0)\n\ts_barrier" ::: "memory");
    }
}

// ---------- fallback (round-1 style) if ws is too small ----------------------
__global__ void __launch_bounds__(256, 2)
corr_fallback(const float* __restrict__ in1, const float* __restrict__ in2,
              float* __restrict__ out) {
    __shared__ unsigned short s1[ROW_ELEMS];
    __shared__ unsigned short s2[ROW_ELEMS];
    const int tid = threadIdx.x;
    const int b = blockIdx.x / NH, y = blockIdx.x % NH;
    const int lane = tid & 63, wave = tid >> 6;
    const int m_lo = lane & 15, quad = lane >> 4;
    const int asub = wave >> 1, bsub = wave & 1;
    {
        const int x = tid & 63, g0 = tid >> 6;
        const float* p = in1 + ((size_t)b * NC * NH + y) * NW + x;
        for (int i = 0; i < 8; ++i) {
            const int chunk = g0 * 8 + i;
            bf16x8 v = load_pack8(p, chunk * 8);
            *(bf16x8*)&s1[sw_addr(x, chunk)] = v;
        }
    }
    __syncthreads();
    bf16x8 afrag[2][8];
    for (int mm = 0; mm < 2; ++mm) {
        const int x = 32 * asub + 16 * mm + m_lo;
        for (int kb = 0; kb < 8; ++kb)
            afrag[mm][kb] = *(const bf16x8*)&s1[sw_addr(x, 4 * kb + quad)];
    }
    const float scale = 1.0f / 256.0f;
    for (int dyi = 0; dyi < ND; ++dyi) {
        const int ys = y + 2 * dyi - 20;
        float* ob = out + (((size_t)b * (ND * ND) + (size_t)dyi * ND) * NH + y) * NW;
        if ((unsigned)ys >= (unsigned)NH) {
            for (int i = tid; i < ND * NW; i += 256)
                ob[(size_t)(i >> 6) * HW + (i & 63)] = 0.0f;
            continue;
        }
        __syncthreads();
        {
            const int x = tid & 63, g0 = tid >> 6;
            const float* p = in2 + ((size_t)b * NC * NH + ys) * NW + x;
            for (int i = 0; i < 8; ++i) {
                const int chunk = g0 * 8 + i;
                bf16x8 v = load_pack8(p, chunk * 8);
                *(bf16x8*)&s2[sw_addr(x, chunk)] = v;
            }
        }
        __syncthreads();
        f32x4 acc[2][2];
        for (int mm = 0; mm < 2; ++mm)
            for (int nn = 0; nn < 2; ++nn) acc[mm][nn] = (f32x4){0.f, 0.f, 0.f, 0.f};
        for (int nn = 0; nn < 2; ++nn) {
            const int xpp = 32 * bsub + 16 * nn + m_lo;
            for (int kb = 0; kb < 8; ++kb) {
                bf16x8 bfrag = *(const bf16x8*)&s2[sw_addr(xpp, 4 * kb + quad)];
                acc[0][nn] = __builtin_amdgcn_mfma_f32_16x16x32_bf16(afrag[0][kb], bfrag, acc[0][nn], 0, 0, 0);
                acc[1][nn] = __builtin_amdgcn_mfma_f32_16x16x32_bf16(afrag[1][kb], bfrag, acc[1][nn], 0, 0, 0);
            }
        }
        for (int mm = 0; mm < 2; ++mm)
            for (int nn = 0; nn < 2; ++nn) {
                const int xb = 32 * asub + 16 * mm + 4 * quad;
                const int xpp = 32 * bsub + 16 * nn + m_lo;
                for (int r = 0; r < 4; ++r) {
                    const int x = xb + r, d = xpp - x;
                    if (d >= -20 && d <= 20 && !(d & 1))
                        ob[(size_t)((d + 20) >> 1) * HW + x] = acc[mm][nn][r] * scale;
                }
            }
        for (int i = tid; i < ND * 20; i += 256) {
            const int dxi = i / 20, j = i - dxi * 20;
            const int dx = 2 * dxi - 20, a = dx < 0 ? -dx : dx;
            if (j < a) {
                const int x = dx < 0 ? j : (NW - dx + j);
                ob[(size_t)dxi * HW + x] = 0.0f;
            }
        }
    }
}

extern "C" void kernel_launch(void* const* d_in, const int* in_sizes, int n_in,
                              void* d_out, int out_size, void* d_ws, size_t ws_size,
                              hipStream_t stream) {
    const float* in1 = (const float*)d_in[0];
    const float* in2 = (const float*)d_in[1];
    float* out = (float*)d_out;
    const size_t need = (size_t)NB * NH * ROW_ELEMS * sizeof(unsigned short);
    if (ws_size >= need) {
        convert_in2<<<dim3(NWG), dim3(256), 0, stream>>>(in2, (unsigned short*)d_ws);
        corr_main<<<dim3(256), dim3(768), 0, stream>>>(in1, (const unsigned short*)d_ws, out);
    } else {
        corr_fallback<<<dim3(NWG), dim3(256), 0, stream>>>(in1, in2, out);
    }
}